// Round 2
// baseline (903.194 us; speedup 1.0000x reference)
//
#include <hip/hip_runtime.h>
#include <hip/hip_bf16.h>
#include <cstdint>
#include <cstddef>

#define Bn 64
#define Mn 512
#define Dn 2048
#define Kn 32
#define EPSF 1e-12f

typedef __attribute__((ext_vector_type(8))) __bf16 bf16x8;
typedef __attribute__((ext_vector_type(4))) __bf16 bf16x4;
typedef __attribute__((ext_vector_type(4))) float f32x4;

// ---------------- K0: W f32 -> bf16 once --------------------------------------
// Keeps K1's W loads at 2 bf16x8/iter (no per-wave reconvert of 256 KB W).
__global__ __launch_bounds__(256) void k0_wcvt(const float* __restrict__ W,
                                               __bf16* __restrict__ wbf) {
  int i = (blockIdx.x * 256 + threadIdx.x) * 4;
  f32x4 v = *(const f32x4*)(W + i);
  bf16x4 o;
  o[0] = (__bf16)v[0]; o[1] = (__bf16)v[1]; o[2] = (__bf16)v[2]; o[3] = (__bf16)v[3];
  *(bf16x4*)(wbf + i) = o;
}

// ---------------- K1: logits (bf16 MFMA) + fused softmax -> saT bf16 + colsum --
// 4 blocks/CU (waves (g,h) = (row-group, D-half), LDS pair-combine).
// Blocks iterate b DESCENDING: LLC (256 MiB ~= |x|) ends holding low-b x most
// recently; K3 then reads ascending and LLC-hits instead of HBM. No xbf store
// (round-1 showed the 134 MB write exactly canceled what it saved downstream).
// C/D layout: lane&15 = k, (lane>>4)*4+r = m (verified mapping).
__global__ __launch_bounds__(256, 4) void k1_logits_softmax(const float* __restrict__ x,
                                                            const __bf16* __restrict__ Wb,
                                                            __bf16* __restrict__ saT,
                                                            float* __restrict__ colsum) {
  __shared__ float red[2][64][9];   // pair-combine buffer (stride 9: no bank clash)
  int wv = threadIdx.x >> 6, lane = threadIdx.x & 63;
  int g = wv & 1, h = wv >> 1;
  int mr = lane & 15, q = lane >> 4;
  int blk = 1023 - blockIdx.x;      // descending-b sweep (LLC recency for K3)
  int row0 = blk * 32 + g * 16;     // 16 blocks per b; rows never cross b
  int b = blk >> 4;
  const float* xp = x + (size_t)(row0 + mr) * Dn + h * 1024 + q * 8;
  const __bf16* wp0 = Wb + (size_t)mr * Dn + h * 1024 + q * 8;
  const __bf16* wp1 = Wb + (size_t)(mr + 16) * Dn + h * 1024 + q * 8;
  f32x4 acc0 = {0.f, 0.f, 0.f, 0.f};
  f32x4 acc1 = {0.f, 0.f, 0.f, 0.f};
  float sqa = 0.f, sqb = 0.f;       // split ssq chains (halve serial FMA dep)
#pragma unroll 2
  for (int s = 0; s < 32; ++s) {
    f32x4 xa = *(const f32x4*)(xp + s * 32);
    f32x4 xb = *(const f32x4*)(xp + s * 32 + 4);
    bf16x8 b0 = *(const bf16x8*)(wp0 + s * 32);
    bf16x8 b1 = *(const bf16x8*)(wp1 + s * 32);
    bf16x8 af;
    af[0] = (__bf16)xa[0]; af[1] = (__bf16)xa[1];
    af[2] = (__bf16)xa[2]; af[3] = (__bf16)xa[3];
    af[4] = (__bf16)xb[0]; af[5] = (__bf16)xb[1];
    af[6] = (__bf16)xb[2]; af[7] = (__bf16)xb[3];
    sqa = fmaf(xa[0], xa[0], sqa); sqb = fmaf(xa[1], xa[1], sqb);
    sqa = fmaf(xa[2], xa[2], sqa); sqb = fmaf(xa[3], xa[3], sqb);
    sqa = fmaf(xb[0], xb[0], sqa); sqb = fmaf(xb[1], xb[1], sqb);
    sqa = fmaf(xb[2], xb[2], sqa); sqb = fmaf(xb[3], xb[3], sqb);
    acc0 = __builtin_amdgcn_mfma_f32_16x16x32_bf16(af, b0, acc0, 0, 0, 0);
    acc1 = __builtin_amdgcn_mfma_f32_16x16x32_bf16(af, b1, acc1, 0, 0, 0);
  }
  float ssq = sqa + sqb;
  // combine D-half partials across wave pairs (g,h=1) -> (g,h=0)
  if (h == 1) {
#pragma unroll
    for (int r = 0; r < 4; ++r) { red[g][lane][r] = acc0[r]; red[g][lane][4 + r] = acc1[r]; }
    red[g][lane][8] = ssq;
  }
  __syncthreads();
  if (h == 1) return;
#pragma unroll
  for (int r = 0; r < 4; ++r) { acc0[r] += red[g][lane][r]; acc1[r] += red[g][lane][4 + r]; }
  ssq += red[g][lane][8];
  // row sumsq: lane (mr,q) holds quarter of row row0+mr
  ssq += __shfl_xor(ssq, 16);
  ssq += __shfl_xor(ssq, 32);
  float invb = 1.f / fmaxf(sqrtf(ssq), EPSF);
  float cs0 = 0.f, cs1 = 0.f;
  bf16x4 v40, v41;
#pragma unroll
  for (int r = 0; r < 4; ++r) {
    float inv = __shfl(invb, q * 4 + r);        // invnorm of row row0+q*4+r
    float v0 = acc0[r] * inv, v1 = acc1[r] * inv;
    float mx = fmaxf(v0, v1);                   // max over 32 k (16 k-lanes x 2)
    mx = fmaxf(mx, __shfl_xor(mx, 1));
    mx = fmaxf(mx, __shfl_xor(mx, 2));
    mx = fmaxf(mx, __shfl_xor(mx, 4));
    mx = fmaxf(mx, __shfl_xor(mx, 8));
    float e0 = __expf(v0 - mx), e1 = __expf(v1 - mx);
    float sm = e0 + e1;
    sm += __shfl_xor(sm, 1); sm += __shfl_xor(sm, 2);
    sm += __shfl_xor(sm, 4); sm += __shfl_xor(sm, 8);
    float rs = 1.f / sm;
    float sa0 = e0 * rs, sa1 = e1 * rs;
    v40[r] = (__bf16)(sa0 * inv);               // sa' = sa * invnorm
    v41[r] = (__bf16)(sa1 * inv);
    cs0 += sa0; cs1 += sa1;
  }
  int mloc = row0 & 511;
  __bf16* st = saT + ((size_t)(b * Kn + mr)) * Mn + mloc + q * 4;
  *(bf16x4*)st = v40;
  *(bf16x4*)(st + (size_t)16 * Mn) = v41;
  cs0 += __shfl_xor(cs0, 16); cs0 += __shfl_xor(cs0, 32);
  cs1 += __shfl_xor(cs1, 16); cs1 += __shfl_xor(cs1, 32);
  if (lane < 16) {
    atomicAdd(&colsum[b * Kn + mr], cs0);
    atomicAdd(&colsum[b * Kn + mr + 16], cs1);
  }
}

// ---------------- K3: agg = saT @ x via MFMA, fused final normalize ------------
// 64-col chunks, grid 2048 (up to 6 blocks/CU; LDS 5 KB double-buffered saT
// tile, padded stride 40 -> conflict-free b128). x fragments: per-lane scalar
// f32 loads -- 16 n-lanes cover one full 64-B line; ascending b hits LLC thanks
// to K1's descending sweep. Tail: per-b ticket (device-scope); the 32nd block
// of each b recomputes the k4 normalize over its 256 KB slice in place
// (single-writer lines + release fence + acq ticket = split-k-standard).
__global__ __launch_bounds__(256, 6) void k3_agg(const float* __restrict__ x,
                                                 const __bf16* __restrict__ saT,
                                                 const float* __restrict__ colsum,
                                                 const float* __restrict__ cent,
                                                 float* __restrict__ vlad,
                                                 float* __restrict__ ssq,
                                                 unsigned int* __restrict__ done) {
  __shared__ __bf16 tile[2][Kn][40];   // 5.1 KB
  __shared__ float csl[Kn];
  __shared__ int winner;
  __shared__ float rk2[Kn], us2[Kn];
  int b = blockIdx.x >> 5;             // 32 chunks of 64 cols per b
  int chunk = blockIdx.x & 31;
  int t = threadIdx.x;
  int w = t >> 6, lane = t & 63;
  int n = lane & 15, q = lane >> 4;
  int d0 = chunk * 64 + w * 16;        // warp owns 16 d-cols
  int sk = t >> 3, mo = (t & 7) * 4;   // staging: thread -> (k-row, 4 m-cols)
  const __bf16* sg = saT + ((size_t)b * Kn + sk) * Mn + mo;
  if (t < Kn) csl[t] = colsum[b * Kn + t];
  *(bf16x4*)&tile[0][sk][mo] = *(const bf16x4*)sg;   // prologue: tile 0
  const float* xgf = x + (size_t)b * Mn * Dn + d0 + n;
  f32x4 acc[2] = {};
  for (int it = 0; it < 16; ++it) {
    int m0 = it * 32;
    int cb = it & 1;
    __syncthreads();
    bf16x4 stg = {};
    if (it < 15) stg = *(const bf16x4*)(sg + m0 + 32);   // next-tile load early
    const float* xp = xgf + (size_t)(m0 + q * 8) * Dn;
    bf16x8 bv;
#pragma unroll
    for (int j = 0; j < 8; ++j) bv[j] = (__bf16)xp[(size_t)j * Dn];
    bf16x8 a0 = *(const bf16x8*)&tile[cb][n][q * 8];
    bf16x8 a1 = *(const bf16x8*)&tile[cb][n + 16][q * 8];
    acc[0] = __builtin_amdgcn_mfma_f32_16x16x32_bf16(a0, bv, acc[0], 0, 0, 0);
    acc[1] = __builtin_amdgcn_mfma_f32_16x16x32_bf16(a1, bv, acc[1], 0, 0, 0);
    if (it < 15) *(bf16x4*)&tile[cb ^ 1][sk][mo] = stg;  // write other buf
  }
  // epilogue: vlad = agg - colsum*cent (fp32), store + ssq partial atomics
  const float* cg = cent + d0 + n;
#pragma unroll
  for (int kt = 0; kt < 2; ++kt) {
#pragma unroll
    for (int r = 0; r < 4; ++r) {
      int k = kt * 16 + q * 4 + r;
      float vv = acc[kt][r] - csl[k] * cg[(size_t)k * Dn];
      vlad[((size_t)(b * Kn + k)) * Dn + d0 + n] = vv;
      float sq = vv * vv;
      sq += __shfl_xor(sq, 1); sq += __shfl_xor(sq, 2);
      sq += __shfl_xor(sq, 4); sq += __shfl_xor(sq, 8);
      if (n == 0) atomicAdd(&ssq[b * Kn + k], sq);
    }
  }
  // -------- fused k4: last chunk-block of this b normalizes the whole slice ---
  __threadfence();                     // release: vlad stores + ssq adds visible
  if (t == 0) {
    unsigned int prev = __hip_atomic_fetch_add(&done[b], 1u, __ATOMIC_ACQ_REL,
                                               __HIP_MEMORY_SCOPE_AGENT);
    winner = (prev == 31);
  }
  __syncthreads();
  if (!winner) return;
  __threadfence();                     // acquire side
  if (t < Kn) {
    float ss = __hip_atomic_load(&ssq[b * Kn + t], __ATOMIC_RELAXED,
                                 __HIP_MEMORY_SCOPE_AGENT);
    float r = 1.f / fmaxf(sqrtf(ss), EPSF);
    rk2[t] = r;
    us2[t] = ss * r * r;               // = ||u_k||^2 after intra-norm
  }
  __syncthreads();
  float S = 0.f;
#pragma unroll
  for (int k = 0; k < Kn; ++k) S += us2[k];
  float s = 1.f / fmaxf(sqrtf(S), EPSF);
  f32x4* p = (f32x4*)(vlad + (size_t)b * (Kn * Dn));
#pragma unroll 4
  for (int i = 0; i < 64; ++i) {
    int idx = t + 256 * i;             // f32x4 index, 0..16383
    int k = idx >> 9;                  // 512 f32x4 (2048 floats) per k
    f32x4 v = p[idx];
    float sc = rk2[k] * s;
    v[0] *= sc; v[1] *= sc; v[2] *= sc; v[3] *= sc;
    p[idx] = v;
  }
}

extern "C" void kernel_launch(void* const* d_in, const int* in_sizes, int n_in,
                              void* d_out, int out_size, void* d_ws, size_t ws_size,
                              hipStream_t stream) {
  const float* x = (const float*)d_in[0];
  const float* W = (const float*)d_in[1];
  const float* cent = (const float*)d_in[2];
  float* out = (float*)d_out;
  char* ws = (char*)d_ws;
  // ws layout: colsum(8K) | ssq(8K) | done(256B) | pad | wbf(128K) | saT(2M)
  float* colsum = (float*)ws;
  float* ssqb = (float*)(ws + 8192);
  unsigned int* done = (unsigned int*)(ws + 16384);
  __bf16* wbf = (__bf16*)(ws + 32768);
  __bf16* saT = (__bf16*)(ws + 32768 + 131072);
  hipMemsetAsync(ws, 0, 32768, stream);   // zero colsum+ssq+done (graph-capturable)
  k0_wcvt<<<dim3(64), dim3(256), 0, stream>>>(W, wbf);
  k1_logits_softmax<<<dim3(1024), dim3(256), 0, stream>>>(x, wbf, saT, colsum);
  k3_agg<<<dim3(2048), dim3(256), 0, stream>>>(x, saT, colsum, cent, out, ssqb, done);
}

// Round 3
// 447.418 us; speedup vs baseline: 2.0187x; 2.0187x over previous
//
#include <hip/hip_runtime.h>
#include <hip/hip_bf16.h>
#include <cstdint>
#include <cstddef>

#define Bn 64
#define Mn 512
#define Dn 2048
#define Kn 32
#define EPSF 1e-12f

typedef __attribute__((ext_vector_type(8))) __bf16 bf16x8;
typedef __attribute__((ext_vector_type(4))) __bf16 bf16x4;
typedef __attribute__((ext_vector_type(4))) float f32x4;

// ---------------- K0: W f32 -> bf16 once --------------------------------------
__global__ __launch_bounds__(256) void k0_wcvt(const float* __restrict__ W,
                                               __bf16* __restrict__ wbf) {
  int i = (blockIdx.x * 256 + threadIdx.x) * 4;
  f32x4 v = *(const f32x4*)(W + i);
  bf16x4 o;
  o[0] = (__bf16)v[0]; o[1] = (__bf16)v[1]; o[2] = (__bf16)v[2]; o[3] = (__bf16)v[3];
  *(bf16x4*)(wbf + i) = o;
}

// ---------------- K1: logits (bf16 MFMA) + fused softmax -> saT bf16 + colsum --
// CHANNEL-STAGGER: all k1 waves previously walked columns in lockstep (s=0,1,..)
// with row stride 8 KB == 32 channel-units and block stride == 0 mod Nch, so at
// any instant the whole GPU hit ~1/16 of the HBM channels (measured 1.5 TB/s).
// Per-block phase rotation s' = (s + 5*blk) & 31 spreads simultaneous accesses
// over all column phases -> all channels. Accumulation order change only.
__global__ __launch_bounds__(256, 4) void k1_logits_softmax(const float* __restrict__ x,
                                                            const __bf16* __restrict__ Wb,
                                                            __bf16* __restrict__ saT,
                                                            float* __restrict__ colsum) {
  __shared__ float red[2][64][9];   // pair-combine buffer (stride 9: no bank clash)
  int wv = threadIdx.x >> 6, lane = threadIdx.x & 63;
  int g = wv & 1, h = wv >> 1;
  int mr = lane & 15, q = lane >> 4;
  int blk = 1023 - blockIdx.x;      // descending-b sweep (LLC recency for K3)
  int ph = (blk * 5) & 31;          // per-block column-phase (channel stagger)
  int row0 = blk * 32 + g * 16;     // 16 blocks per b; rows never cross b
  int b = blk >> 4;
  const float* xp = x + (size_t)(row0 + mr) * Dn + h * 1024 + q * 8;
  const __bf16* wp0 = Wb + (size_t)mr * Dn + h * 1024 + q * 8;
  const __bf16* wp1 = Wb + (size_t)(mr + 16) * Dn + h * 1024 + q * 8;
  f32x4 acc0 = {0.f, 0.f, 0.f, 0.f};
  f32x4 acc1 = {0.f, 0.f, 0.f, 0.f};
  float sqa = 0.f, sqb = 0.f;       // split ssq chains
#pragma unroll 2
  for (int s = 0; s < 32; ++s) {
    int s2 = (s + ph) & 31;         // staggered column step (scalar)
    f32x4 xa = *(const f32x4*)(xp + s2 * 32);
    f32x4 xb = *(const f32x4*)(xp + s2 * 32 + 4);
    bf16x8 b0 = *(const bf16x8*)(wp0 + s2 * 32);
    bf16x8 b1 = *(const bf16x8*)(wp1 + s2 * 32);
    bf16x8 af;
    af[0] = (__bf16)xa[0]; af[1] = (__bf16)xa[1];
    af[2] = (__bf16)xa[2]; af[3] = (__bf16)xa[3];
    af[4] = (__bf16)xb[0]; af[5] = (__bf16)xb[1];
    af[6] = (__bf16)xb[2]; af[7] = (__bf16)xb[3];
    sqa = fmaf(xa[0], xa[0], sqa); sqb = fmaf(xa[1], xa[1], sqb);
    sqa = fmaf(xa[2], xa[2], sqa); sqb = fmaf(xa[3], xa[3], sqb);
    sqa = fmaf(xb[0], xb[0], sqa); sqb = fmaf(xb[1], xb[1], sqb);
    sqa = fmaf(xb[2], xb[2], sqa); sqb = fmaf(xb[3], xb[3], sqb);
    acc0 = __builtin_amdgcn_mfma_f32_16x16x32_bf16(af, b0, acc0, 0, 0, 0);
    acc1 = __builtin_amdgcn_mfma_f32_16x16x32_bf16(af, b1, acc1, 0, 0, 0);
  }
  float ssq = sqa + sqb;
  if (h == 1) {
#pragma unroll
    for (int r = 0; r < 4; ++r) { red[g][lane][r] = acc0[r]; red[g][lane][4 + r] = acc1[r]; }
    red[g][lane][8] = ssq;
  }
  __syncthreads();
  if (h == 1) return;
#pragma unroll
  for (int r = 0; r < 4; ++r) { acc0[r] += red[g][lane][r]; acc1[r] += red[g][lane][4 + r]; }
  ssq += red[g][lane][8];
  ssq += __shfl_xor(ssq, 16);
  ssq += __shfl_xor(ssq, 32);
  float invb = 1.f / fmaxf(sqrtf(ssq), EPSF);
  float cs0 = 0.f, cs1 = 0.f;
  bf16x4 v40, v41;
#pragma unroll
  for (int r = 0; r < 4; ++r) {
    float inv = __shfl(invb, q * 4 + r);        // invnorm of row row0+q*4+r
    float v0 = acc0[r] * inv, v1 = acc1[r] * inv;
    float mx = fmaxf(v0, v1);                   // max over 32 k
    mx = fmaxf(mx, __shfl_xor(mx, 1));
    mx = fmaxf(mx, __shfl_xor(mx, 2));
    mx = fmaxf(mx, __shfl_xor(mx, 4));
    mx = fmaxf(mx, __shfl_xor(mx, 8));
    float e0 = __expf(v0 - mx), e1 = __expf(v1 - mx);
    float sm = e0 + e1;
    sm += __shfl_xor(sm, 1); sm += __shfl_xor(sm, 2);
    sm += __shfl_xor(sm, 4); sm += __shfl_xor(sm, 8);
    float rs = 1.f / sm;
    float sa0 = e0 * rs, sa1 = e1 * rs;
    v40[r] = (__bf16)(sa0 * inv);               // sa' = sa * invnorm
    v41[r] = (__bf16)(sa1 * inv);
    cs0 += sa0; cs1 += sa1;
  }
  int mloc = row0 & 511;
  __bf16* st = saT + ((size_t)(b * Kn + mr)) * Mn + mloc + q * 4;
  *(bf16x4*)st = v40;
  *(bf16x4*)(st + (size_t)16 * Mn) = v41;
  cs0 += __shfl_xor(cs0, 16); cs0 += __shfl_xor(cs0, 32);
  cs1 += __shfl_xor(cs1, 16); cs1 += __shfl_xor(cs1, 32);
  if (lane < 16) {
    atomicAdd(&colsum[b * Kn + mr], cs0);
    atomicAdd(&colsum[b * Kn + mr + 16], cs1);
  }
}

// ---------------- K3: agg = saT @ x via MFMA ----------------------------------
// Round-0 PROVEN structure restored: full saT panel staged once (33 KB, stride
// 520 -> conflict-light b128), ONE barrier, NO barriers in the m-loop (compiler
// free to software-pipeline the scalar x loads across iterations — round-2's
// per-iter barrier version measured 556 us, latency-serialized).
// Plus: 64-col chunks (256 B = 1 channel-unit granularity; the old 128-col
// chunks hit only even channel units) and per-block m-phase stagger so
// simultaneous row accesses spread over all 16 m-phases.
#define AS 520
__global__ __launch_bounds__(256, 4) void k3_agg(const float* __restrict__ x,
                                                 const __bf16* __restrict__ saT,
                                                 const float* __restrict__ colsum,
                                                 const float* __restrict__ cent,
                                                 float* __restrict__ vlad,
                                                 float* __restrict__ ssq) {
  __shared__ __bf16 sal[Kn * AS];   // ~33 KB
  __shared__ float csl[Kn];
  int b = blockIdx.x >> 5;          // 32 chunks of 64 cols per b
  int chunk = blockIdx.x & 31;
  int ph = (blockIdx.x * 5) & 15;   // per-block m-phase (channel stagger)
  int t = threadIdx.x;
  const __bf16* sg = saT + (size_t)b * Kn * Mn;
#pragma unroll
  for (int i = 0; i < 8; ++i) {
    int u = t + 256 * i;            // 2048 units of 8 bf16
    int kr = u >> 6, off = (u & 63) * 8;
    *(bf16x8*)&sal[kr * AS + off] = *(const bf16x8*)(sg + (size_t)kr * Mn + off);
  }
  if (t < Kn) csl[t] = colsum[b * Kn + t];
  __syncthreads();
  int w = t >> 6, lane = t & 63;
  int n = lane & 15, q = lane >> 4;
  int d0 = chunk * 64 + w * 16;     // warp owns 16 d-cols
  const float* xg = x + (size_t)b * Mn * Dn + d0 + n;
  f32x4 acc[2] = {};
  for (int it = 0; it < 16; ++it) {
    int m0 = ((it + ph) & 15) * 32;
    bf16x8 a0 = *(const bf16x8*)&sal[n * AS + m0 + q * 8];
    bf16x8 a1 = *(const bf16x8*)&sal[(n + 16) * AS + m0 + q * 8];
    const float* xp = xg + (size_t)(m0 + q * 8) * Dn;
    bf16x8 bv;
#pragma unroll
    for (int j = 0; j < 8; ++j) bv[j] = (__bf16)xp[(size_t)j * Dn];
    acc[0] = __builtin_amdgcn_mfma_f32_16x16x32_bf16(a0, bv, acc[0], 0, 0, 0);
    acc[1] = __builtin_amdgcn_mfma_f32_16x16x32_bf16(a1, bv, acc[1], 0, 0, 0);
  }
  // epilogue: vlad = agg - colsum*cent (fp32), store + ssq partial atomics
  const float* cg = cent + d0 + n;
#pragma unroll
  for (int kt = 0; kt < 2; ++kt) {
#pragma unroll
    for (int r = 0; r < 4; ++r) {
      int k = kt * 16 + q * 4 + r;
      float vv = acc[kt][r] - csl[k] * cg[(size_t)k * Dn];
      vlad[((size_t)(b * Kn + k)) * Dn + d0 + n] = vv;
      float sq = vv * vv;
      sq += __shfl_xor(sq, 1); sq += __shfl_xor(sq, 2);
      sq += __shfl_xor(sq, 4); sq += __shfl_xor(sq, 8);
      if (n == 0) atomicAdd(&ssq[b * Kn + k], sq);
    }
  }
}

// ---------------- K4: intra-normalize per (b,k) + global L2 normalize, in place
__global__ __launch_bounds__(256) void k4_norm(float* __restrict__ out,
                                               const float* __restrict__ ssq) {
  __shared__ float rk[Kn];
  __shared__ float us[Kn];
  int b = blockIdx.x >> 4;
  int t = threadIdx.x;
  if (t < Kn) {
    float ss = ssq[b * Kn + t];
    float r = 1.f / fmaxf(sqrtf(ss), EPSF);
    rk[t] = r;
    us[t] = ss * r * r;   // = ||u_k||^2 after intra-norm
  }
  __syncthreads();
  float S = 0.f;
#pragma unroll
  for (int k = 0; k < Kn; ++k) S += us[k];
  float s = 1.f / fmaxf(sqrtf(S), EPSF);
  int chunk = blockIdx.x & 15;
  size_t base = (size_t)b * (Kn * Dn) + (size_t)chunk * 4096;
  f32x4* p = (f32x4*)(out + base);
#pragma unroll
  for (int i = 0; i < 4; ++i) {
    int idx = t + 256 * i;                        // float4 index, 0..1023
    int k = (chunk * 4096 + idx * 4) >> 11;       // 2048 floats per k
    f32x4 v = p[idx];
    float sc = rk[k] * s;
    v[0] *= sc; v[1] *= sc; v[2] *= sc; v[3] *= sc;
    p[idx] = v;
  }
}

extern "C" void kernel_launch(void* const* d_in, const int* in_sizes, int n_in,
                              void* d_out, int out_size, void* d_ws, size_t ws_size,
                              hipStream_t stream) {
  const float* x = (const float*)d_in[0];
  const float* W = (const float*)d_in[1];
  const float* cent = (const float*)d_in[2];
  float* out = (float*)d_out;
  char* ws = (char*)d_ws;
  // ws layout: colsum(8K) | ssq(8K) | wbf(128K) | saT(2M)
  float* colsum = (float*)ws;
  float* ssqb = (float*)(ws + 8192);
  __bf16* wbf = (__bf16*)(ws + 16384);
  __bf16* saT = (__bf16*)(ws + 16384 + 131072);
  hipMemsetAsync(ws, 0, 16384, stream);   // zero colsum+ssq (graph-capturable)
  k0_wcvt<<<dim3(64), dim3(256), 0, stream>>>(W, wbf);
  k1_logits_softmax<<<dim3(1024), dim3(256), 0, stream>>>(x, wbf, saT, colsum);
  k3_agg<<<dim3(2048), dim3(256), 0, stream>>>(x, saT, colsum, cent, out, ssqb);
  k4_norm<<<dim3(1024), dim3(256), 0, stream>>>(out, ssqb);
}

// Round 4
// 443.305 us; speedup vs baseline: 2.0374x; 1.0093x over previous
//
#include <hip/hip_runtime.h>
#include <hip/hip_bf16.h>
#include <cstdint>
#include <cstddef>

#define Bn 64
#define Mn 512
#define Dn 2048
#define Kn 32
#define EPSF 1e-12f

typedef __attribute__((ext_vector_type(8))) __bf16 bf16x8;
typedef __attribute__((ext_vector_type(4))) __bf16 bf16x4;
typedef __attribute__((ext_vector_type(4))) float f32x4;

// ---------------- K0: W f32 -> bf16 once --------------------------------------
__global__ __launch_bounds__(256) void k0_wcvt(const float* __restrict__ W,
                                               __bf16* __restrict__ wbf) {
  int i = (blockIdx.x * 256 + threadIdx.x) * 4;
  f32x4 v = *(const f32x4*)(W + i);
  bf16x4 o;
  o[0] = (__bf16)v[0]; o[1] = (__bf16)v[1]; o[2] = (__bf16)v[2]; o[3] = (__bf16)v[3];
  *(bf16x4*)(wbf + i) = o;
}

// ---------------- K1: LDS-staged logits + fused softmax ------------------------
// THEORY: direct-from-global MFMA fragment loads (16 rows x 8KB stride, 16B
// pieces interleaved at 32B within each 128B) ran at 1.5 TB/s; contiguous
// streams run at 6.3-6.6 TB/s on this chip. So stage via LDS: each wave reads
// 4 WHOLE rows as sequential 1KB bursts (perfect DRAM page behavior), converts
// f32->bf16 + ssq in flight, writes a 64KB XOR-swizzled tile (byte ^=
// (row&7)<<4 -> conflict-free b128 reads at the power-of-2 row stride, G4).
// One barrier, then 4 waves MFMA over K-quarters, one combine. Barriers never
// sit inside a load loop (round-2 lesson). Descending-b sweep kept for K3 LLC.
__global__ __launch_bounds__(256, 2) void k1_logits_softmax(const float* __restrict__ x,
                                                            const __bf16* __restrict__ Wb,
                                                            __bf16* __restrict__ saT,
                                                            float* __restrict__ colsum) {
  __shared__ char salb[16 * 4096];        // 64 KB: 16 rows x 2048 bf16, swizzled
  int wv = threadIdx.x >> 6, lane = threadIdx.x & 63;
  int h = wv;                             // wave id: staging rows / K-quarter
  int mr = lane & 15, q = lane >> 4;
  int blk = 2047 - blockIdx.x;            // descending-b (LLC recency for K3)
  int row0 = blk * 16;
  int b = blk >> 5;                       // 32 blocks per b
  // ---- stage: wave h loads rows row0+4h..+3, full D, sequential 1KB bursts ---
  const float* xr = x + ((size_t)row0 + h * 4) * Dn + lane * 4;
  float rs0, rs1, rs2, rs3;
#pragma unroll
  for (int r4 = 0; r4 < 4; ++r4) {
    const float* rp = xr + (size_t)r4 * Dn;
    int lrow = h * 4 + r4;
    int rbase = lrow << 12;
    int rxor = (lrow & 7) << 4;
    float sq = 0.f;
#pragma unroll
    for (int i = 0; i < 8; ++i) {
      f32x4 v = *(const f32x4*)(rp + i * 256);
      bf16x4 o;
      o[0] = (__bf16)v[0]; o[1] = (__bf16)v[1];
      o[2] = (__bf16)v[2]; o[3] = (__bf16)v[3];
      sq = fmaf(v[0], v[0], sq); sq = fmaf(v[1], v[1], sq);
      sq = fmaf(v[2], v[2], sq); sq = fmaf(v[3], v[3], sq);
      *(bf16x4*)(salb + rbase + ((i * 512 + lane * 8) ^ rxor)) = o;
    }
    sq += __shfl_xor(sq, 1); sq += __shfl_xor(sq, 2); sq += __shfl_xor(sq, 4);
    sq += __shfl_xor(sq, 8); sq += __shfl_xor(sq, 16); sq += __shfl_xor(sq, 32);
    if (r4 == 0) rs0 = sq; else if (r4 == 1) rs1 = sq;
    else if (r4 == 2) rs2 = sq; else rs3 = sq;
  }
  __syncthreads();                         // staged tile visible to all waves
  // ---- MFMA: wave h covers K-quarter [h*512, (h+1)*512) ----------------------
  const __bf16* wp0 = Wb + (size_t)mr * Dn + h * 512 + q * 8;
  const __bf16* wp1 = wp0 + (size_t)16 * Dn;
  int rbase = mr << 12;
  int rxor = (mr & 7) << 4;
  int cbase = h * 1024 + q * 16;           // byte offset of this lane's k-slice
  f32x4 acc0 = {0.f, 0.f, 0.f, 0.f};
  f32x4 acc1 = {0.f, 0.f, 0.f, 0.f};
#pragma unroll 4
  for (int ks = 0; ks < 16; ++ks) {
    bf16x8 af = *(const bf16x8*)(salb + rbase + ((cbase + ks * 64) ^ rxor));
    bf16x8 b0 = *(const bf16x8*)(wp0 + ks * 32);
    bf16x8 b1 = *(const bf16x8*)(wp1 + ks * 32);
    acc0 = __builtin_amdgcn_mfma_f32_16x16x32_bf16(af, b0, acc0, 0, 0, 0);
    acc1 = __builtin_amdgcn_mfma_f32_16x16x32_bf16(af, b1, acc1, 0, 0, 0);
  }
  __syncthreads();                         // all LDS frag reads done -> overlay OK
  float* redf = (float*)salb;              // overlay: [3][64][8] partials + ssq[16]
  if (h) {
    float* rp2 = redf + ((h - 1) * 64 + lane) * 8;
#pragma unroll
    for (int r = 0; r < 4; ++r) { rp2[r] = acc0[r]; rp2[4 + r] = acc1[r]; }
  }
  if (lane == 0) {
    float* spw = redf + 1536 + h * 4;
    spw[0] = rs0; spw[1] = rs1; spw[2] = rs2; spw[3] = rs3;
  }
  __syncthreads();
  if (h) return;
  // ---- wave 0: 4-way combine + softmax epilogue (identical math to r0-r3) ----
#pragma unroll
  for (int r = 0; r < 4; ++r) {
    acc0[r] += redf[(0 * 64 + lane) * 8 + r] + redf[(1 * 64 + lane) * 8 + r]
             + redf[(2 * 64 + lane) * 8 + r];
    acc1[r] += redf[(0 * 64 + lane) * 8 + 4 + r] + redf[(1 * 64 + lane) * 8 + 4 + r]
             + redf[(2 * 64 + lane) * 8 + 4 + r];
  }
  const float* sp = redf + 1536;
  float cs0 = 0.f, cs1 = 0.f;
  bf16x4 v40, v41;
#pragma unroll
  for (int r = 0; r < 4; ++r) {
    float ssr = sp[q * 4 + r];                  // ssq of row row0+q*4+r
    float inv = 1.f / fmaxf(sqrtf(ssr), EPSF);
    float v0 = acc0[r] * inv, v1 = acc1[r] * inv;
    float mx = fmaxf(v0, v1);                   // max over 32 k (16 k-lanes x 2)
    mx = fmaxf(mx, __shfl_xor(mx, 1));
    mx = fmaxf(mx, __shfl_xor(mx, 2));
    mx = fmaxf(mx, __shfl_xor(mx, 4));
    mx = fmaxf(mx, __shfl_xor(mx, 8));
    float e0 = __expf(v0 - mx), e1 = __expf(v1 - mx);
    float sm = e0 + e1;
    sm += __shfl_xor(sm, 1); sm += __shfl_xor(sm, 2);
    sm += __shfl_xor(sm, 4); sm += __shfl_xor(sm, 8);
    float rsi = 1.f / sm;
    float sa0 = e0 * rsi, sa1 = e1 * rsi;
    v40[r] = (__bf16)(sa0 * inv);               // sa' = sa * invnorm
    v41[r] = (__bf16)(sa1 * inv);
    cs0 += sa0; cs1 += sa1;
  }
  int mloc = row0 & 511;                        // m-offset within this b
  __bf16* st = saT + ((size_t)(b * Kn + mr)) * Mn + mloc + q * 4;
  *(bf16x4*)st = v40;
  *(bf16x4*)(st + (size_t)16 * Mn) = v41;
  cs0 += __shfl_xor(cs0, 16); cs0 += __shfl_xor(cs0, 32);
  cs1 += __shfl_xor(cs1, 16); cs1 += __shfl_xor(cs1, 32);
  if (lane < 16) {
    atomicAdd(&colsum[b * Kn + mr], cs0);
    atomicAdd(&colsum[b * Kn + mr + 16], cs1);
  }
}

// ---------------- K3: agg = saT @ x via MFMA (round-0 proven form, 85 us) ------
// Full saT panel staged once (33 KB, stride 520 -> conflict-light b128), ONE
// barrier, no barriers in the m-loop. x fragment loads are scalar f32: each
// instruction covers full 64-B lines (8 rows x 64B). Ascending b hits LLC
// thanks to K1's descending sweep.
#define AS 520
__global__ __launch_bounds__(256) void k3_agg(const float* __restrict__ x,
                                              const __bf16* __restrict__ saT,
                                              const float* __restrict__ colsum,
                                              const float* __restrict__ cent,
                                              float* __restrict__ vlad,
                                              float* __restrict__ ssq) {
  __shared__ __bf16 sal[Kn * AS];   // ~33 KB
  __shared__ float csl[Kn];
  int b = blockIdx.x >> 4;
  int dchunk = (blockIdx.x & 15) * 128;
  int t = threadIdx.x;
  const __bf16* sg = saT + (size_t)b * Kn * Mn;
#pragma unroll
  for (int i = 0; i < 8; ++i) {
    int u = t + 256 * i;            // 2048 units of 8 bf16
    int kr = u >> 6, off = (u & 63) * 8;
    *(bf16x8*)&sal[kr * AS + off] = *(const bf16x8*)(sg + (size_t)kr * Mn + off);
  }
  if (t < Kn) csl[t] = colsum[b * Kn + t];
  __syncthreads();
  int w = t >> 6, lane = t & 63;
  int n = lane & 15, q = lane >> 4;
  int d0 = dchunk + w * 32;
  const float* xg = x + (size_t)b * Mn * Dn;
  f32x4 acc[2][2] = {};
  for (int m0 = 0; m0 < Mn; m0 += 32) {
    bf16x8 a0 = *(const bf16x8*)&sal[n * AS + m0 + q * 8];
    bf16x8 a1 = *(const bf16x8*)&sal[(n + 16) * AS + m0 + q * 8];
#pragma unroll
    for (int dt = 0; dt < 2; ++dt) {
      const float* xp = xg + (size_t)(m0 + q * 8) * Dn + d0 + dt * 16 + n;
      bf16x8 bv;
#pragma unroll
      for (int j = 0; j < 8; ++j) bv[j] = (__bf16)xp[(size_t)j * Dn];
      acc[dt][0] = __builtin_amdgcn_mfma_f32_16x16x32_bf16(a0, bv, acc[dt][0], 0, 0, 0);
      acc[dt][1] = __builtin_amdgcn_mfma_f32_16x16x32_bf16(a1, bv, acc[dt][1], 0, 0, 0);
    }
  }
  // epilogue: vlad = agg - colsum*cent (fp32), store + ssq partial atomics
#pragma unroll
  for (int dt = 0; dt < 2; ++dt) {
#pragma unroll
    for (int kt = 0; kt < 2; ++kt) {
#pragma unroll
      for (int r = 0; r < 4; ++r) {
        int k = kt * 16 + q * 4 + r;
        int d = d0 + dt * 16 + n;
        float vv = acc[dt][kt][r] - csl[k] * cent[(size_t)k * Dn + d];
        vlad[((size_t)(b * Kn + k)) * Dn + d] = vv;
        float sq = vv * vv;
        sq += __shfl_xor(sq, 1); sq += __shfl_xor(sq, 2);
        sq += __shfl_xor(sq, 4); sq += __shfl_xor(sq, 8);
        if (n == 0) atomicAdd(&ssq[b * Kn + k], sq);
      }
    }
  }
}

// ---------------- K4: intra-normalize per (b,k) + global L2 normalize, in place
__global__ __launch_bounds__(256) void k4_norm(float* __restrict__ out,
                                               const float* __restrict__ ssq) {
  __shared__ float rk[Kn];
  __shared__ float us[Kn];
  int b = blockIdx.x >> 4;
  int t = threadIdx.x;
  if (t < Kn) {
    float ss = ssq[b * Kn + t];
    float r = 1.f / fmaxf(sqrtf(ss), EPSF);
    rk[t] = r;
    us[t] = ss * r * r;   // = ||u_k||^2 after intra-norm
  }
  __syncthreads();
  float S = 0.f;
#pragma unroll
  for (int k = 0; k < Kn; ++k) S += us[k];
  float s = 1.f / fmaxf(sqrtf(S), EPSF);
  int chunk = blockIdx.x & 15;
  size_t base = (size_t)b * (Kn * Dn) + (size_t)chunk * 4096;
  f32x4* p = (f32x4*)(out + base);
#pragma unroll
  for (int i = 0; i < 4; ++i) {
    int idx = t + 256 * i;                        // float4 index, 0..1023
    int k = (chunk * 4096 + idx * 4) >> 11;       // 2048 floats per k
    f32x4 v = p[idx];
    float sc = rk[k] * s;
    v[0] *= sc; v[1] *= sc; v[2] *= sc; v[3] *= sc;
    p[idx] = v;
  }
}

extern "C" void kernel_launch(void* const* d_in, const int* in_sizes, int n_in,
                              void* d_out, int out_size, void* d_ws, size_t ws_size,
                              hipStream_t stream) {
  const float* x = (const float*)d_in[0];
  const float* W = (const float*)d_in[1];
  const float* cent = (const float*)d_in[2];
  float* out = (float*)d_out;
  char* ws = (char*)d_ws;
  // ws layout: colsum(8K) | ssq(8K) | wbf(128K) | saT(2M)
  float* colsum = (float*)ws;
  float* ssqb = (float*)(ws + 8192);
  __bf16* wbf = (__bf16*)(ws + 16384);
  __bf16* saT = (__bf16*)(ws + 16384 + 131072);
  hipMemsetAsync(ws, 0, 16384, stream);   // zero colsum+ssq (graph-capturable)
  k0_wcvt<<<dim3(64), dim3(256), 0, stream>>>(W, wbf);
  k1_logits_softmax<<<dim3(2048), dim3(256), 0, stream>>>(x, wbf, saT, colsum);
  k3_agg<<<dim3(1024), dim3(256), 0, stream>>>(x, saT, colsum, cent, out, ssqb);
  k4_norm<<<dim3(1024), dim3(256), 0, stream>>>(out, ssqb);
}